// Round 5
// baseline (136.312 us; speedup 1.0000x reference)
//
#include <hip/hip_runtime.h>
#include <math.h>

#define H_  128
#define N_  64
#define L_  4096
#define B_  8
#define LC  128
#define NCH 32     // chunks per sequence (L_/LC)
#define SPB 4      // sequences (batches) per block
#define RS  136    // f16 row stride for T/G/M/U/C (272B: stride%32dw==4 -> bank-floor reads)
#define RSE 132    // f32 row stride for E/Y

typedef _Float16 f16;
typedef _Float16 half8 __attribute__((ext_vector_type(8)));
typedef _Float16 f16x4 __attribute__((ext_vector_type(4)));
typedef _Float16 f16x2 __attribute__((ext_vector_type(2)));
typedef float    floatx4 __attribute__((ext_vector_type(4)));

// per-(h,n) scalar constants; double only for the one-time closed forms
__device__ __forceinline__ void dss_consts(int h, int n,
    const float* __restrict__ Lre, const float* __restrict__ Lim,
    const float* __restrict__ Wri, const float* __restrict__ lstep,
    float& af, float& bf, float& crf, float& cif, float& qrf, float& qif)
{
    const float stepf = expf(lstep[h]);
    const float a  = stepf * Lre[h*N_ + n];     // f32, matches reference P build
    const float bp = stepf * Lim[h*N_ + n];
    const double ad = (double)a, bd = (double)bp;
    const double em = exp(ad);
    const double rre = em * cos(bd), rim = em * sin(bd);
    const double eL = exp(ad * (double)L_);
    const double rLre = eL * cos(bd * (double)L_), rLim = eL * sin(bd * (double)L_);
    const double nre = 1.0 - rLre, nim = -rLim;       // s = (1 - r^L)/(1 - r)
    const double dre = 1.0 - rre,  dim = -rim;
    const double dm  = dre*dre + dim*dim;
    const double sre = (nre*dre + nim*dim) / dm;
    const double sim = (nim*dre - nre*dim) / dm;
    const double wre = (double)Wri[(h*N_ + n)*2 + 0];
    const double wim = (double)Wri[(h*N_ + n)*2 + 1];
    const double lre = (double)Lre[h*N_ + n], lim = (double)Lim[h*N_ + n];
    const double lm  = lre*lre + lim*lim;
    const double wor = (wre*lre + wim*lim) / lm;      // W / Lambda
    const double woi = (wim*lre - wre*lim) / lm;
    const double sm  = sre*sre + sim*sim + 1e-7;      // c = (W/L)*conj(s)/(|s|^2+eps)
    const double eC  = exp(ad * (double)LC);
    af = a; bf = bp;
    crf = (float)((wor*sre + woi*sim) / sm);
    cif = (float)((woi*sre - wor*sim) / sm);
    qrf = (float)(eC * cos(bd * (double)LC));
    qif = (float)(eC * sin(bd * (double)LC));
}

// One block per (h, half-of-batches). T/G/M built in LDS, consumed by MFMA.
// T[i][j] = (i>=j) ? K'[i-j] : 0   (K'[0] += D)
// G[2m+im][k] = {Re,Im}(r_m^{127-k});  M[j][2m+ri] = {16Re,-16Im}(c_m r_m^{j+1})
__global__ __launch_bounds__(256, 1)
void dss_fused(const float* __restrict__ u,
               const float* __restrict__ Lre, const float* __restrict__ Lim,
               const float* __restrict__ Wri, const float* __restrict__ Dv,
               const float* __restrict__ lstep, float* __restrict__ out)
{
    __shared__ f16   sT[LC][RS];          // 34.0 KB
    __shared__ f16   sG[LC][RS];          // 34.0 KB
    __shared__ f16   sM[LC][RS];          // 34.0 KB
    __shared__ f16   sU[2][NCH][RS];      // 17.0 KB (double-buffered u)
    __shared__ float sE[NCH][RSE];        // 16.5 KB (end-states, then y)
    __shared__ f16   sC[NCH][RS];         //  8.5 KB (carries /16)
    __shared__ float sKp[2][LC];
    __shared__ float sK[LC];
    __shared__ float sQ[2*N_];
    __shared__ float s_a[N_], s_b[N_], s_cr[N_], s_ci[N_];

    const int t = threadIdx.x;
    const int h = blockIdx.x >> 1;
    const int s = blockIdx.x & 1;         // batches s*4 .. s*4+3

    // prefetch batch 0's u into registers (latency hides under the build)
    float4 fr0, fr1, fr2, fr3;
    {
        const float4* up = reinterpret_cast<const float4*>(u + ((size_t)(s*SPB)*H_ + h) * L_);
        fr0 = up[t]; fr1 = up[t+256]; fr2 = up[t+512]; fr3 = up[t+768];
    }

    if (t < N_) {
        float a, b, cr, ci, qr, qi;
        dss_consts(h, t, Lre, Lim, Wri, lstep, a, b, cr, ci, qr, qi);
        s_a[t]=a; s_b[t]=b; s_cr[t]=cr; s_ci[t]=ci;
        sQ[2*t]=qr; sQ[2*t+1]=qi;
    }
    __syncthreads();

    // K lags (all 256 threads: 128 lags x 2 mode-halves)
    {
        const int lag = t & 127, hf = t >> 7;
        float acc = 0.f;
        #pragma unroll
        for (int m = 0; m < 32; ++m) {
            const int n = hf*32 + m;
            const float ex = expf(s_a[n] * (float)lag);
            float sn, cs; sincosf(s_b[n] * (float)lag, &sn, &cs);
            acc = fmaf(ex, s_cr[n]*cs - s_ci[n]*sn, acc);   // Re(c r^lag)
        }
        sKp[hf][lag] = acc;
    }
    __syncthreads();
    if (t < LC) {
        float kv = sKp[0][t] + sKp[1][t];
        if (t == 0) kv += Dv[h];
        sK[t] = kv;
    }
    __syncthreads();

    // fill T/G/M in LDS (8 half8 slots per matrix per thread)
    #pragma unroll
    for (int i = 0; i < 8; ++i) {
        const int e8 = t + i*256;
        const int row = e8 >> 4, c0 = (e8 & 15) * 8;
        {   // T
            half8 pv;
            #pragma unroll
            for (int j = 0; j < 8; ++j) {
                const int col = c0 + j;
                pv[j] = (f16)((row >= col) ? sK[row - col] : 0.f);
            }
            *reinterpret_cast<half8*>(&sT[row][c0]) = pv;
        }
        {   // G
            const int m = row >> 1, im = row & 1;
            const float a = s_a[m], b = s_b[m];
            half8 pv;
            #pragma unroll
            for (int j = 0; j < 8; ++j) {
                const float p = (float)(127 - (c0 + j));
                const float ex = expf(a * p);
                float sn, cs; sincosf(b * p, &sn, &cs);
                pv[j] = (f16)(im ? ex*sn : ex*cs);
            }
            *reinterpret_cast<half8*>(&sG[row][c0]) = pv;
        }
        {   // M (x16 scale; carries stored /16)
            const float p = (float)(row + 1);
            half8 pv;
            #pragma unroll
            for (int mm = 0; mm < 4; ++mm) {
                const int m = (c0 >> 1) + mm;
                const float ex = expf(s_a[m] * p);
                float sn, cs; sincosf(s_b[m] * p, &sn, &cs);
                const float pr = ex*cs, pi = ex*sn;
                pv[2*mm]   = (f16)( 16.f * (s_cr[m]*pr - s_ci[m]*pi));
                pv[2*mm+1] = (f16)(-16.f * (s_cr[m]*pi + s_ci[m]*pr));
            }
            *reinterpret_cast<half8*>(&sM[row][c0]) = pv;
        }
    }
    // (visibility of fills is covered by the per-batch post-stage barrier)

    const int w  = t >> 6;     // wave -> n-tiles {2w, 2w+1}
    const int l  = t & 63;
    const int lr = l & 15;
    const int lg = l >> 4;

    #pragma unroll
    for (int i = 0; i < SPB; ++i) {
        const int cur = i & 1;

        // stage this batch's u (from regs) into sU[cur]
        #pragma unroll
        for (int j = 0; j < 4; ++j) {
            const float4 v = (j==0)?fr0:(j==1)?fr1:(j==2)?fr2:fr3;
            const int e4 = t + j*256;
            const int row = e4 >> 5, c4 = (e4 & 31) * 4;
            f16x4 pv = { (f16)v.x, (f16)v.y, (f16)v.z, (f16)v.w };
            *reinterpret_cast<f16x4*>(&sU[cur][row][c4]) = pv;
        }
        // prefetch next batch's u
        if (i < SPB-1) {
            const float4* up = reinterpret_cast<const float4*>(
                u + ((size_t)(s*SPB + i + 1)*H_ + h) * L_);
            fr0 = up[t]; fr1 = up[t+256]; fr2 = up[t+512]; fr3 = up[t+768];
        }
        __syncthreads();

        floatx4 accA[2][2] = {};   // y accumulators (phases A + C)
        floatx4 accB[2][2] = {};   // end-state accumulators (phase B)

        // phases A (Y_loc = U*T) and B (E = U*G)
        #pragma unroll
        for (int ks = 0; ks < 4; ++ks) {
            const int ko = ks*32 + lg*8;
            const half8 a0 = *reinterpret_cast<const half8*>(&sU[cur][lr     ][ko]);
            const half8 a1 = *reinterpret_cast<const half8*>(&sU[cur][16 + lr][ko]);
            #pragma unroll
            for (int nt = 0; nt < 2; ++nt) {
                const int ncol = (2*w + nt)*16 + lr;
                const half8 bT = *reinterpret_cast<const half8*>(&sT[ncol][ko]);
                const half8 bG = *reinterpret_cast<const half8*>(&sG[ncol][ko]);
                accA[0][nt] = __builtin_amdgcn_mfma_f32_16x16x32_f16(a0, bT, accA[0][nt], 0, 0, 0);
                accA[1][nt] = __builtin_amdgcn_mfma_f32_16x16x32_f16(a1, bT, accA[1][nt], 0, 0, 0);
                accB[0][nt] = __builtin_amdgcn_mfma_f32_16x16x32_f16(a0, bG, accB[0][nt], 0, 0, 0);
                accB[1][nt] = __builtin_amdgcn_mfma_f32_16x16x32_f16(a1, bG, accB[1][nt], 0, 0, 0);
            }
        }
        // spill end-state fragments
        #pragma unroll
        for (int mt = 0; mt < 2; ++mt)
            #pragma unroll
            for (int nt = 0; nt < 2; ++nt)
                #pragma unroll
                for (int j = 0; j < 4; ++j)
                    sE[mt*16 + lg*4 + j][(2*w + nt)*16 + lr] = accB[mt][nt][j];
        __syncthreads();

        // carry scan (wave 0; lane = mode)
        if (w == 0) {
            const float qre = sQ[2*l], qim = sQ[2*l+1];
            float cr = 0.f, ci = 0.f;
            #pragma unroll
            for (int k = 0; k < NCH; ++k) {
                const float er = sE[k][2*l], ei = sE[k][2*l+1];
                *reinterpret_cast<f16x2*>(&sC[k][2*l]) =
                    (f16x2){ (f16)(cr * 0.0625f), (f16)(ci * 0.0625f) };
                const float ncr = fmaf(qre, cr, fmaf(-qim, ci, er));
                const float nci = fmaf(qre, ci, fmaf( qim, cr, ei));
                cr = ncr; ci = nci;
            }
        }
        __syncthreads();

        // phase C: Y += C * M
        #pragma unroll
        for (int ks = 0; ks < 4; ++ks) {
            const int ko = ks*32 + lg*8;
            const half8 a0 = *reinterpret_cast<const half8*>(&sC[lr     ][ko]);
            const half8 a1 = *reinterpret_cast<const half8*>(&sC[16 + lr][ko]);
            #pragma unroll
            for (int nt = 0; nt < 2; ++nt) {
                const int ncol = (2*w + nt)*16 + lr;
                const half8 bM = *reinterpret_cast<const half8*>(&sM[ncol][ko]);
                accA[0][nt] = __builtin_amdgcn_mfma_f32_16x16x32_f16(a0, bM, accA[0][nt], 0, 0, 0);
                accA[1][nt] = __builtin_amdgcn_mfma_f32_16x16x32_f16(a1, bM, accA[1][nt], 0, 0, 0);
            }
        }

        // epilogue: fragments -> sE (dead after scan), then coalesced float4 out
        #pragma unroll
        for (int mt = 0; mt < 2; ++mt)
            #pragma unroll
            for (int nt = 0; nt < 2; ++nt)
                #pragma unroll
                for (int j = 0; j < 4; ++j)
                    sE[mt*16 + lg*4 + j][(2*w + nt)*16 + lr] = accA[mt][nt][j];
        __syncthreads();
        {
            float4* op = reinterpret_cast<float4*>(out + ((size_t)(s*SPB + i)*H_ + h) * L_);
            #pragma unroll
            for (int j = 0; j < 4; ++j) {
                const int e4 = t + j*256;
                const int row = e4 >> 5, c4 = (e4 & 31) * 4;
                op[e4] = *reinterpret_cast<const float4*>(&sE[row][c4]);
            }
        }
    }
}

extern "C" void kernel_launch(void* const* d_in, const int* in_sizes, int n_in,
                              void* d_out, int out_size, void* d_ws, size_t ws_size,
                              hipStream_t stream) {
    const float* u  = (const float*)d_in[0];
    const float* lr = (const float*)d_in[1];
    const float* li = (const float*)d_in[2];
    const float* w  = (const float*)d_in[3];
    const float* dv = (const float*)d_in[4];
    const float* ls = (const float*)d_in[5];
    float* out = (float*)d_out;
    dss_fused<<<dim3(H_*2), dim3(256), 0, stream>>>(u, lr, li, w, dv, ls, out);
}

// Round 6
// 96.304 us; speedup vs baseline: 1.4154x; 1.4154x over previous
//
#include <hip/hip_runtime.h>
#include <math.h>

#define H_  128
#define N_  64
#define L_  4096
#define B_  8
#define LC  128
#define NCH 32     // L_/LC

typedef _Float16 f16;
typedef _Float16 half8 __attribute__((ext_vector_type(8)));
typedef _Float16 f16x4 __attribute__((ext_vector_type(4)));
typedef _Float16 f16x2 __attribute__((ext_vector_type(2)));
typedef float    floatx4 __attribute__((ext_vector_type(4)));

// ws layout (bytes): T | G | M (each H_*LC*LC f16) | q (H_*N_*2 f32)
#define WS_T 0
#define WS_G ((size_t)H_*LC*LC*2)
#define WS_M ((size_t)2*H_*LC*LC*2)
#define WS_Q ((size_t)3*H_*LC*LC*2)

// ---- native-transcendental helpers (v_exp_f32 / v_sin_f32 / v_cos_f32) ----
__device__ __forceinline__ float fexp(float x) {           // e^x
    return __builtin_amdgcn_exp2f(x * 1.4426950408889634f);
}
__device__ __forceinline__ void fcis(float th, float& cs, float& sn) {
    // cos/sin of th (radians); f64 revolution reduction (|th| up to ~3000)
    double rev = (double)th * 0.15915494309189535;
    rev -= floor(rev);
    const float r = (float)rev;                            // in [0,1)
    sn = __builtin_amdgcn_sinf(r);                         // sin(2πr)
    cs = __builtin_amdgcn_cosf(r);
}
__device__ __forceinline__ void fcis64(double th, float& cs, float& sn) {
    double rev = th * 0.15915494309189535;
    rev -= floor(rev);
    const float r = (float)rev;
    sn = __builtin_amdgcn_sinf(r);
    cs = __builtin_amdgcn_cosf(r);
}

// per-(h,n) scalar constants — all-native, no libm slow paths
__device__ __forceinline__ void dss_consts(int h, int n,
    const float* __restrict__ Lre, const float* __restrict__ Lim,
    const float* __restrict__ Wri, const float* __restrict__ lstep,
    float& af, float& bf, float& crf, float& cif, float& qrf, float& qif)
{
    const float stepf = fexp(lstep[h]);
    const float a  = stepf * Lre[h*N_ + n];     // f32, matches reference P build
    const float bp = stepf * Lim[h*N_ + n];
    // r = e^a cis(b)
    const float em = fexp(a);
    float rcs, rsn; fcis(bp, rcs, rsn);
    const float rre = em*rcs, rim = em*rsn;
    // r^L  (b*4096 computed in f64; 4096 is pow2 so the product is exact)
    const float eL = fexp(a * 4096.0f);
    float cL, sL; fcis64((double)bp * 4096.0, cL, sL);
    const float rLre = eL*cL, rLim = eL*sL;
    // s = (1 - r^L) / (1 - r)
    const float nre = 1.0f - rLre, nim = -rLim;
    const float dre = 1.0f - rre,  dim = -rim;
    const float dm  = dre*dre + dim*dim;
    const float sre = (nre*dre + nim*dim) / dm;
    const float sim = (nim*dre - nre*dim) / dm;
    // W / Lambda
    const float wre = Wri[(h*N_ + n)*2 + 0];
    const float wim = Wri[(h*N_ + n)*2 + 1];
    const float lre = Lre[h*N_ + n], lim = Lim[h*N_ + n];
    const float lm  = lre*lre + lim*lim;
    const float wor = (wre*lre + wim*lim) / lm;
    const float woi = (wim*lre - wre*lim) / lm;
    // c = (W/Lambda) * conj(s) / (|s|^2 + eps)
    const float sm  = sre*sre + sim*sim + 1e-7f;
    crf = (wor*sre + woi*sim) / sm;
    cif = (woi*sre - wor*sim) / sm;
    // q = r^128
    const float eC = fexp(a * 128.0f);
    float cC, sC; fcis64((double)bp * 128.0, cC, sC);
    qrf = eC*cC; qif = eC*sC;
    af = a; bf = bp;
}

// ---------------- K1: build T/G/M/q, one block per (h, matrix) ----------------
// T[i*128+j] = (i>=j) ? K'[i-j] : 0      (K'[0] = K[0]+D)
// G[(2m)*128+k]   = Re(r_m^{127-k}),  G[(2m+1)*128+k] = Im(r_m^{127-k})
// M[j*128+2m]     = 16*Re(c_m r_m^{j+1}), M[j*128+2m+1] = -16*Im(c_m r_m^{j+1})
__global__ __launch_bounds__(256)
void dss_prep(const float* __restrict__ Lre, const float* __restrict__ Lim,
              const float* __restrict__ Wri, const float* __restrict__ Dv,
              const float* __restrict__ lstep, char* __restrict__ ws)
{
    __shared__ float s_a[N_], s_b[N_], s_cr[N_], s_ci[N_];
    __shared__ float sKp[2][128];
    __shared__ float sK[128];
    const int h = blockIdx.x;
    const int which = blockIdx.y;
    const int t = threadIdx.x;

    if (t < N_) {
        float a, b, cr, ci, qr, qi;
        dss_consts(h, t, Lre, Lim, Wri, lstep, a, b, cr, ci, qr, qi);
        s_a[t] = a; s_b[t] = b; s_cr[t] = cr; s_ci[t] = ci;
        if (which == 0) {
            float* qg = (float*)(ws + WS_Q) + (size_t)h*N_*2;
            qg[2*t] = qr; qg[2*t+1] = qi;
        }
    }
    __syncthreads();

    if (which == 0) {          // ---- T (local causal Toeplitz of K) ----
        const int lag = t & 127, hf = t >> 7;   // 128 lags x 2 mode-halves
        float acc = 0.f;
        #pragma unroll
        for (int m = 0; m < 32; ++m) {
            const int n = hf*32 + m;
            const float ex = fexp(s_a[n] * (float)lag);
            float cs, sn; fcis(s_b[n] * (float)lag, cs, sn);
            acc = fmaf(ex, s_cr[n]*cs - s_ci[n]*sn, acc);   // Re(c r^lag)
        }
        sKp[hf][lag] = acc;
        __syncthreads();
        if (t < 128) {
            float kv = sKp[0][t] + sKp[1][t];
            if (t == 0) kv += Dv[h];           // fold D*u into diagonal
            sK[t] = kv;
        }
        __syncthreads();
        f16* Tg = (f16*)(ws + WS_T) + (size_t)h*LC*LC;
        #pragma unroll
        for (int i = 0; i < 8; ++i) {
            const int e8 = t + i*256;
            const int row = e8 >> 4, c0 = (e8 & 15) * 8;
            half8 pv;
            #pragma unroll
            for (int j = 0; j < 8; ++j) {
                const int col = c0 + j;
                pv[j] = (f16)((row >= col) ? sK[row - col] : 0.f);
            }
            *reinterpret_cast<half8*>(&Tg[row*LC + c0]) = pv;
        }
    } else if (which == 1) {   // ---- G (end-state gather) ----
        f16* Gg = (f16*)(ws + WS_G) + (size_t)h*LC*LC;
        #pragma unroll
        for (int i = 0; i < 8; ++i) {
            const int e8 = t + i*256;
            const int row = e8 >> 4, c0 = (e8 & 15) * 8;
            const int m = row >> 1, im = row & 1;
            const float a = s_a[m], b = s_b[m];
            half8 pv;
            #pragma unroll
            for (int j = 0; j < 8; ++j) {
                const float p = (float)(127 - (c0 + j));
                const float ex = fexp(a * p);
                float cs, sn; fcis(b * p, cs, sn);
                pv[j] = (f16)(im ? ex*sn : ex*cs);
            }
            *reinterpret_cast<half8*>(&Gg[row*LC + c0]) = pv;
        }
    } else {                   // ---- M (carry broadcast, x16 scale) ----
        f16* Mg = (f16*)(ws + WS_M) + (size_t)h*LC*LC;
        #pragma unroll
        for (int i = 0; i < 8; ++i) {
            const int e8 = t + i*256;
            const int row = e8 >> 4, c0 = (e8 & 15) * 8;   // 4 modes per slot
            const float p = (float)(row + 1);
            half8 pv;
            #pragma unroll
            for (int mm = 0; mm < 4; ++mm) {
                const int m = (c0 >> 1) + mm;
                const float ex = fexp(s_a[m] * p);
                float cs, sn; fcis(s_b[m] * p, cs, sn);
                const float pr = ex*cs, pi = ex*sn;
                pv[2*mm]   = (f16)( 16.f * (s_cr[m]*pr - s_ci[m]*pi));  //  16*Re
                pv[2*mm+1] = (f16)(-16.f * (s_cr[m]*pi + s_ci[m]*pr));  // -16*Im
            }
            *reinterpret_cast<half8*>(&Mg[row*LC + c0]) = pv;
        }
    }
}

// ---------------- K2: main — 3 batched GEMMs + carry scan ----------------
__global__ __launch_bounds__(256, 4)
void dss_main(const float* __restrict__ u, const char* __restrict__ ws,
              float* __restrict__ out)
{
    __shared__ f16   sU[NCH][132];    // u chunks, f16, padded rows (8.25 KB)
    __shared__ float sE[NCH][132];    // end-states f32, later y (16.5 KB)
    __shared__ f16   sC[NCH][132];    // carries (f16, scaled 1/16)

    const int t  = threadIdx.x;
    const int bh = blockIdx.x;
    const int h  = bh & (H_-1);
    const f16* Tg = (const f16*)(ws + WS_T) + (size_t)h*LC*LC;
    const f16* Gg = (const f16*)(ws + WS_G) + (size_t)h*LC*LC;
    const f16* Mg = (const f16*)(ws + WS_M) + (size_t)h*LC*LC;
    const float* qg = (const float*)(ws + WS_Q) + (size_t)h*N_*2;

    // stage u -> f16 LDS
    {
        const float4* up = reinterpret_cast<const float4*>(u + (size_t)bh * L_);
        #pragma unroll
        for (int i = 0; i < L_/4/256; ++i) {
            const int e4 = t + i*256;
            const float4 v = up[e4];
            const int row = e4 >> 5, c4 = (e4 & 31) * 4;
            f16x4 pv = { (f16)v.x, (f16)v.y, (f16)v.z, (f16)v.w };
            *reinterpret_cast<f16x4*>(&sU[row][c4]) = pv;
        }
    }
    __syncthreads();

    const int w  = t >> 6;     // wave 0..3 -> n-tiles {2w, 2w+1}
    const int l  = t & 63;
    const int lr = l & 15;     // tile row/col index
    const int lg = l >> 4;     // k-group / output-row group

    floatx4 accA[2][2] = {};   // [mtile][nt] — y accumulators (phases A + C)
    floatx4 accB[2][2] = {};   // end-state accumulators (phase B)

    // phases A (Y_loc = U*T) and B (E = U*G), fused over the K loop
    #pragma unroll
    for (int ks = 0; ks < 4; ++ks) {
        const int ko = ks*32 + lg*8;
        const half8 a0 = *reinterpret_cast<const half8*>(&sU[lr     ][ko]);
        const half8 a1 = *reinterpret_cast<const half8*>(&sU[16 + lr][ko]);
        #pragma unroll
        for (int nt = 0; nt < 2; ++nt) {
            const int ncol = (2*w + nt)*16 + lr;
            const half8 bT = *reinterpret_cast<const half8*>(&Tg[ncol*LC + ko]);
            const half8 bG = *reinterpret_cast<const half8*>(&Gg[ncol*LC + ko]);
            accA[0][nt] = __builtin_amdgcn_mfma_f32_16x16x32_f16(a0, bT, accA[0][nt], 0, 0, 0);
            accA[1][nt] = __builtin_amdgcn_mfma_f32_16x16x32_f16(a1, bT, accA[1][nt], 0, 0, 0);
            accB[0][nt] = __builtin_amdgcn_mfma_f32_16x16x32_f16(a0, bG, accB[0][nt], 0, 0, 0);
            accB[1][nt] = __builtin_amdgcn_mfma_f32_16x16x32_f16(a1, bG, accB[1][nt], 0, 0, 0);
        }
    }
    // spill E fragments to LDS
    #pragma unroll
    for (int mt = 0; mt < 2; ++mt)
        #pragma unroll
        for (int nt = 0; nt < 2; ++nt)
            #pragma unroll
            for (int j = 0; j < 4; ++j)
                sE[mt*16 + lg*4 + j][(2*w + nt)*16 + lr] = accB[mt][nt][j];
    __syncthreads();

    // carry scan (wave 0; lane = mode), grouped LDS preload (8-deep)
    if (w == 0) {
        const float qre = qg[2*l], qim = qg[2*l+1];
        float cr = 0.f, ci = 0.f;
        #pragma unroll
        for (int gb = 0; gb < 4; ++gb) {
            float2 E[8];
            #pragma unroll
            for (int j = 0; j < 8; ++j)
                E[j] = *reinterpret_cast<const float2*>(&sE[gb*8 + j][2*l]);
            #pragma unroll
            for (int j = 0; j < 8; ++j) {
                *reinterpret_cast<f16x2*>(&sC[gb*8 + j][2*l]) =
                    (f16x2){ (f16)(cr * 0.0625f), (f16)(ci * 0.0625f) };
                const float ncr = fmaf(qre, cr, fmaf(-qim, ci, E[j].x));
                const float nci = fmaf(qre, ci, fmaf( qim, cr, E[j].y));
                cr = ncr; ci = nci;
            }
        }
    }
    __syncthreads();

    // phase C: Y += C * M (chained into accA)
    #pragma unroll
    for (int ks = 0; ks < 4; ++ks) {
        const int ko = ks*32 + lg*8;
        const half8 a0 = *reinterpret_cast<const half8*>(&sC[lr     ][ko]);
        const half8 a1 = *reinterpret_cast<const half8*>(&sC[16 + lr][ko]);
        #pragma unroll
        for (int nt = 0; nt < 2; ++nt) {
            const int ncol = (2*w + nt)*16 + lr;
            const half8 bM = *reinterpret_cast<const half8*>(&Mg[ncol*LC + ko]);
            accA[0][nt] = __builtin_amdgcn_mfma_f32_16x16x32_f16(a0, bM, accA[0][nt], 0, 0, 0);
            accA[1][nt] = __builtin_amdgcn_mfma_f32_16x16x32_f16(a1, bM, accA[1][nt], 0, 0, 0);
        }
    }

    // epilogue: fragments -> LDS (sE dead after scan), then coalesced float4 out
    #pragma unroll
    for (int mt = 0; mt < 2; ++mt)
        #pragma unroll
        for (int nt = 0; nt < 2; ++nt)
            #pragma unroll
            for (int j = 0; j < 4; ++j)
                sE[mt*16 + lg*4 + j][(2*w + nt)*16 + lr] = accA[mt][nt][j];
    __syncthreads();
    {
        float4* op = reinterpret_cast<float4*>(out + (size_t)bh * L_);
        #pragma unroll
        for (int i = 0; i < L_/4/256; ++i) {
            const int e4 = t + i*256;
            const int row = e4 >> 5, c4 = (e4 & 31) * 4;
            op[e4] = *reinterpret_cast<const float4*>(&sE[row][c4]);
        }
    }
}

extern "C" void kernel_launch(void* const* d_in, const int* in_sizes, int n_in,
                              void* d_out, int out_size, void* d_ws, size_t ws_size,
                              hipStream_t stream) {
    const float* u  = (const float*)d_in[0];
    const float* lr = (const float*)d_in[1];
    const float* li = (const float*)d_in[2];
    const float* w  = (const float*)d_in[3];
    const float* dv = (const float*)d_in[4];
    const float* ls = (const float*)d_in[5];
    float* out = (float*)d_out;
    char* ws = (char*)d_ws;
    dss_prep<<<dim3(H_, 3), dim3(256), 0, stream>>>(lr, li, w, dv, ls, ws);
    dss_main<<<dim3(B_*H_), dim3(256), 0, stream>>>(u, ws, out);
}

// Round 7
// 95.351 us; speedup vs baseline: 1.4296x; 1.0100x over previous
//
#include <hip/hip_runtime.h>
#include <math.h>

#define H_  128
#define N_  64
#define L_  4096
#define B_  8
#define LC  128
#define NCH 32     // chunks (L_/LC)
#define TPB 512    // 8 waves; wave w owns output cols [16w,16w+16)

typedef _Float16 f16;
typedef _Float16 half8 __attribute__((ext_vector_type(8)));
typedef _Float16 f16x4 __attribute__((ext_vector_type(4)));
typedef _Float16 f16x2 __attribute__((ext_vector_type(2)));
typedef float    floatx4 __attribute__((ext_vector_type(4)));

// ---- native-transcendental helpers (v_exp_f32 / v_sin_f32 / v_cos_f32) ----
__device__ __forceinline__ float fexp(float x) {           // e^x
    return __builtin_amdgcn_exp2f(x * 1.4426950408889634f);
}
__device__ __forceinline__ void fcis(float th, float& cs, float& sn) {
    // cos/sin of th (radians); f64 revolution reduction (|th| up to ~3000)
    double rev = (double)th * 0.15915494309189535;
    rev -= floor(rev);
    const float r = (float)rev;                            // [0,1)
    sn = __builtin_amdgcn_sinf(r);                         // sin(2πr)
    cs = __builtin_amdgcn_cosf(r);
}
__device__ __forceinline__ void fcis64(double th, float& cs, float& sn) {
    double rev = th * 0.15915494309189535;
    rev -= floor(rev);
    const float r = (float)rev;
    sn = __builtin_amdgcn_sinf(r);
    cs = __builtin_amdgcn_cosf(r);
}

// Fully fused: one kernel, no workspace. Per block (h, s): 2 batches.
// y[l] = sum_j K'[l-j] u[j] (local) + Re(carry * c r^{l+1}) ; K'[0]=K[0]+D
__global__ __launch_bounds__(TPB, 4)   // cap VGPR at 128 -> 2 blocks/CU
void dss_one(const float* __restrict__ u,
             const float* __restrict__ Lre, const float* __restrict__ Lim,
             const float* __restrict__ Wri, const float* __restrict__ Dv,
             const float* __restrict__ lstep, float* __restrict__ out)
{
    __shared__ f16   sU[NCH][132];    // u chunks f16          (8.25 KB)
    __shared__ float sE[NCH][132];    // end-states f32, then y (16.5 KB)
    __shared__ f16   sC[NCH][132];    // carries /16            (8.25 KB)
    __shared__ float sKp[2][LC];
    __shared__ float sK[LC];
    __shared__ float s_a[N_], s_b[N_], s_cr[N_], s_ci[N_], sQ[2*N_];

    const int t = threadIdx.x;
    const int h = blockIdx.x & (H_-1);
    const int s = blockIdx.x >> 7;        // 0..3 -> batches {2s, 2s+1}

    // prefetch batch 2s's u (hides under consts/K/frag build)
    float4 p0, p1;
    {
        const float4* up = reinterpret_cast<const float4*>(u + ((size_t)(2*s)*H_ + h) * L_);
        p0 = up[t]; p1 = up[t + TPB];
    }

    // ---- consts (lanes 0..63 = modes), all-native ----
    if (t < N_) {
        const int n = t;
        const float stepf = fexp(lstep[h]);
        const float a  = stepf * Lre[h*N_ + n];
        const float bp = stepf * Lim[h*N_ + n];
        const float em = fexp(a);
        float rcs, rsn; fcis(bp, rcs, rsn);
        const float rre = em*rcs, rim = em*rsn;
        const float eL = fexp(a * 4096.0f);
        float cL, sL; fcis64((double)bp * 4096.0, cL, sL);
        const float rLre = eL*cL, rLim = eL*sL;
        const float nre = 1.0f - rLre, nim = -rLim;      // s = (1-r^L)/(1-r)
        const float dre = 1.0f - rre,  dim = -rim;
        const float dm  = dre*dre + dim*dim;
        const float sre = (nre*dre + nim*dim) / dm;
        const float sim = (nim*dre - nre*dim) / dm;
        const float wre = Wri[(h*N_ + n)*2 + 0];
        const float wim = Wri[(h*N_ + n)*2 + 1];
        const float lre = Lre[h*N_ + n], lim = Lim[h*N_ + n];
        const float lm  = lre*lre + lim*lim;
        const float wor = (wre*lre + wim*lim) / lm;      // W/Lambda
        const float woi = (wim*lre - wre*lim) / lm;
        const float sm  = sre*sre + sim*sim + 1e-7f;
        s_a[n] = a; s_b[n] = bp;
        s_cr[n] = (wor*sre + woi*sim) / sm;
        s_ci[n] = (woi*sre - wor*sim) / sm;
        const float eC = fexp(a * 128.0f);               // q = r^128
        float cC, sC2; fcis64((double)bp * 128.0, cC, sC2);
        sQ[2*n] = eC*cC; sQ[2*n+1] = eC*sC2;
    }
    __syncthreads();

    // ---- K lag sums (256 threads: 128 lags x 2 mode-halves) ----
    if (t < 256) {
        const int lag = t & 127, hf = t >> 7;
        float acc = 0.f;
        #pragma unroll
        for (int m = 0; m < 32; ++m) {
            const int n = hf*32 + m;
            const float ex = fexp(s_a[n] * (float)lag);
            float cs, sn; fcis(s_b[n] * (float)lag, cs, sn);
            acc = fmaf(ex, s_cr[n]*cs - s_ci[n]*sn, acc);   // Re(c r^lag)
        }
        sKp[hf][lag] = acc;
    }
    __syncthreads();
    if (t < LC) {
        float kv = sKp[0][t] + sKp[1][t];
        if (t == 0) kv += Dv[h];
        sK[t] = kv;
    }
    __syncthreads();

    const int w  = t >> 6;          // wave = n-tile
    const int l  = t & 63;
    const int lr = l & 15;
    const int lg = l >> 4;
    const int pos = w*16 + lr;      // output col / B-row this lane serves

    // ---- build register-resident B fragments (reused across both batches) ----
    half8 bT[4], bG[4], bM[4];
    {
        const int   gm  = pos >> 1, gim = pos & 1;       // G row -> mode/half
        const float ga  = s_a[gm],  gb  = s_b[gm];
        const float pm  = (float)(pos + 1);              // M row power
        #pragma unroll
        for (int ks = 0; ks < 4; ++ks) {
            const int ko = ks*32 + lg*8;
            #pragma unroll
            for (int j = 0; j < 8; ++j) {                // T: causal Toeplitz of K'
                const int col = ko + j;
                bT[ks][j] = (f16)((pos >= col) ? sK[pos - col] : 0.f);
            }
            #pragma unroll
            for (int j = 0; j < 8; ++j) {                // G: {Re,Im}(r^{127-k})
                const float p = (float)(127 - (ko + j));
                const float ex = fexp(ga * p);
                float cs, sn; fcis(gb * p, cs, sn);
                bG[ks][j] = (f16)(gim ? ex*sn : ex*cs);
            }
            #pragma unroll
            for (int mm = 0; mm < 4; ++mm) {             // M: 16*{Re,-Im}(c r^{pos+1})
                const int m = (ko >> 1) + mm;
                const float ex = fexp(s_a[m] * pm);
                float cs, sn; fcis(s_b[m] * pm, cs, sn);
                const float pr = ex*cs, pi = ex*sn;
                bM[ks][2*mm]   = (f16)( 16.f * (s_cr[m]*pr - s_ci[m]*pi));
                bM[ks][2*mm+1] = (f16)(-16.f * (s_cr[m]*pi + s_ci[m]*pr));
            }
        }
    }

    #pragma unroll
    for (int i = 0; i < 2; ++i) {
        // stage u (from prefetched regs)
        #pragma unroll
        for (int j = 0; j < 2; ++j) {
            const float4 v = j ? p1 : p0;
            const int e4 = t + j*TPB;
            const int row = e4 >> 5, c4 = (e4 & 31) * 4;
            f16x4 pv = { (f16)v.x, (f16)v.y, (f16)v.z, (f16)v.w };
            *reinterpret_cast<f16x4*>(&sU[row][c4]) = pv;
        }
        if (i == 0) {   // prefetch next batch
            const float4* up = reinterpret_cast<const float4*>(u + ((size_t)(2*s+1)*H_ + h) * L_);
            p0 = up[t]; p1 = up[t + TPB];
        }
        __syncthreads();

        floatx4 accA[2] = {};   // y (local + carry correction)
        floatx4 accB[2] = {};   // end-states

        #pragma unroll
        for (int ks = 0; ks < 4; ++ks) {       // phases A (U*T) and B (U*G)
            const int ko = ks*32 + lg*8;
            const half8 a0 = *reinterpret_cast<const half8*>(&sU[lr     ][ko]);
            const half8 a1 = *reinterpret_cast<const half8*>(&sU[16 + lr][ko]);
            accA[0] = __builtin_amdgcn_mfma_f32_16x16x32_f16(a0, bT[ks], accA[0], 0, 0, 0);
            accA[1] = __builtin_amdgcn_mfma_f32_16x16x32_f16(a1, bT[ks], accA[1], 0, 0, 0);
            accB[0] = __builtin_amdgcn_mfma_f32_16x16x32_f16(a0, bG[ks], accB[0], 0, 0, 0);
            accB[1] = __builtin_amdgcn_mfma_f32_16x16x32_f16(a1, bG[ks], accB[1], 0, 0, 0);
        }
        #pragma unroll
        for (int mt = 0; mt < 2; ++mt)
            #pragma unroll
            for (int j = 0; j < 4; ++j)
                sE[mt*16 + lg*4 + j][pos] = accB[mt][j];
        __syncthreads();

        // carry scan (wave 0; lane = mode), grouped 8-deep LDS preload
        if (w == 0) {
            const float qre = sQ[2*l], qim = sQ[2*l+1];
            float cr = 0.f, ci = 0.f;
            #pragma unroll
            for (int gb = 0; gb < 4; ++gb) {
                float2 E[8];
                #pragma unroll
                for (int j = 0; j < 8; ++j)
                    E[j] = *reinterpret_cast<const float2*>(&sE[gb*8 + j][2*l]);
                #pragma unroll
                for (int j = 0; j < 8; ++j) {
                    *reinterpret_cast<f16x2*>(&sC[gb*8 + j][2*l]) =
                        (f16x2){ (f16)(cr * 0.0625f), (f16)(ci * 0.0625f) };
                    const float ncr = fmaf(qre, cr, fmaf(-qim, ci, E[j].x));
                    const float nci = fmaf(qre, ci, fmaf( qim, cr, E[j].y));
                    cr = ncr; ci = nci;
                }
            }
        }
        __syncthreads();

        #pragma unroll
        for (int ks = 0; ks < 4; ++ks) {       // phase C: Y += C * M
            const int ko = ks*32 + lg*8;
            const half8 a0 = *reinterpret_cast<const half8*>(&sC[lr     ][ko]);
            const half8 a1 = *reinterpret_cast<const half8*>(&sC[16 + lr][ko]);
            accA[0] = __builtin_amdgcn_mfma_f32_16x16x32_f16(a0, bM[ks], accA[0], 0, 0, 0);
            accA[1] = __builtin_amdgcn_mfma_f32_16x16x32_f16(a1, bM[ks], accA[1], 0, 0, 0);
        }
        #pragma unroll
        for (int mt = 0; mt < 2; ++mt)
            #pragma unroll
            for (int j = 0; j < 4; ++j)
                sE[mt*16 + lg*4 + j][pos] = accA[mt][j];
        __syncthreads();

        {   // coalesced store
            float4* op = reinterpret_cast<float4*>(out + ((size_t)(2*s + i)*H_ + h) * L_);
            #pragma unroll
            for (int j = 0; j < 2; ++j) {
                const int e4 = t + j*TPB;
                const int row = e4 >> 5, c4 = (e4 & 31) * 4;
                op[e4] = *reinterpret_cast<const float4*>(&sE[row][c4]);
            }
        }
        __syncthreads();   // protect sU/sE before next batch overwrites
    }
}

extern "C" void kernel_launch(void* const* d_in, const int* in_sizes, int n_in,
                              void* d_out, int out_size, void* d_ws, size_t ws_size,
                              hipStream_t stream) {
    const float* u  = (const float*)d_in[0];
    const float* lr = (const float*)d_in[1];
    const float* li = (const float*)d_in[2];
    const float* w  = (const float*)d_in[3];
    const float* dv = (const float*)d_in[4];
    const float* ls = (const float*)d_in[5];
    float* out = (float*)d_out;
    dss_one<<<dim3(H_*4), dim3(TPB), 0, stream>>>(u, lr, li, w, dv, ls, out);
}